// Round 9
// baseline (67.199 us; speedup 1.0000x reference)
//
#include <hip/hip_runtime.h>
#include <hip/hip_bf16.h>

#define CIN   64
#define COUT  128
#define TT    256
#define VV    25
#define TV    (TT * VV)   // 6400
#define KW    9
#define PAD   4
#define YROW  28          // padded bf16 y row: 56B -> natural conflict-free
#define YSTR  (TT * YROW) // 7168 shorts per (n,c) plane

typedef __attribute__((ext_vector_type(8))) short short8;   // 8 bf16 (4 VGPRs)
typedef __attribute__((ext_vector_type(4))) float f32x4;

__device__ __forceinline__ unsigned f2b(float f) {          // fp32 -> bf16 bits (RNE)
    unsigned u = __builtin_bit_cast(unsigned, f);
    return (u + 0x7FFFu + ((u >> 16) & 1u)) >> 16;
}
__device__ __forceinline__ float lof(unsigned u) {          // low bf16 -> f32
    return __builtin_bit_cast(float, u << 16);
}
__device__ __forceinline__ float hif(unsigned u) {          // high bf16 -> f32
    return __builtin_bit_cast(float, u & 0xffff0000u);
}
// conv LDS tile swizzle: [row][128B], XOR slot with (row&7)
__device__ __forceinline__ int swz(int row, int cbyte) {
    return row * 128 + ((cbyte & ~15) ^ ((row & 7) << 4)) + (cbyte & 15);
}

// ---------------- Kernel A: 1x1 conv + BN via bf16 MFMA (unchanged R7) ----------------
__global__ __launch_bounds__(256) void conv_mfma(
    const float* __restrict__ x, const float* __restrict__ w,
    const float* __restrict__ cb, const float* __restrict__ gamma,
    const float* __restrict__ beta, const float* __restrict__ rm,
    const float* __restrict__ rv, unsigned short* __restrict__ y)
{
    __shared__ __align__(16) unsigned short Wl[COUT * 64];   // 16 KB, swizzled
    __shared__ __align__(16) unsigned short Xl[128 * 64];    // 16 KB, swizzled [pos][c]
    __shared__ float sc[COUT];
    __shared__ float of[COUT];

    const int pc  = blockIdx.x;       // 0..49
    const int n   = blockIdx.y;       // 0..15
    const int tid = threadIdx.x;
    const int posbase = pc * 128;

    if (tid < COUT) {
        const float s = gamma[tid] * rsqrtf(rv[tid] + 1e-5f);
        sc[tid] = s;
        of[tid] = cb[tid] * s + beta[tid] - rm[tid] * s;
    }
    for (int idx = tid; idx < 2048; idx += 256) {
        const int c4 = idx & 15, o = idx >> 4;
        const f32x4 wv = *(const f32x4*)(w + o * 64 + c4 * 4);
        uint2 pk;
        pk.x = f2b(wv.x) | (f2b(wv.y) << 16);
        pk.y = f2b(wv.z) | (f2b(wv.w) << 16);
        *(uint2*)((char*)Wl + swz(o, c4 * 8)) = pk;
    }
    for (int idx = tid; idx < 2048; idx += 256) {
        const int pos = idx & 127, c4 = idx >> 7;
        const float* xp = x + (size_t)n * CIN * TV + (size_t)(c4 * 4) * TV + posbase + pos;
        const float a0 = xp[0], a1 = xp[TV], a2 = xp[2 * TV], a3 = xp[3 * TV];
        uint2 pk;
        pk.x = f2b(a0) | (f2b(a1) << 16);
        pk.y = f2b(a2) | (f2b(a3) << 16);
        *(uint2*)((char*)Xl + swz(pos, c4 * 8)) = pk;
    }
    __syncthreads();

    const int wv_ = tid >> 6, lane = tid & 63;
    const int lr = lane & 15, lh = lane >> 4;   // lh in 0..3

    short8 afr[2][2];
#pragma unroll
    for (int m0 = 0; m0 < 2; ++m0)
#pragma unroll
        for (int kh = 0; kh < 2; ++kh)
            afr[m0][kh] = *(const short8*)((const char*)Wl +
                              swz(wv_ * 32 + m0 * 16 + lr, kh * 64 + lh * 16));

    f32x4 acc[2][8];
#pragma unroll
    for (int m0 = 0; m0 < 2; ++m0)
#pragma unroll
        for (int n0 = 0; n0 < 8; ++n0) acc[m0][n0] = (f32x4){0.f, 0.f, 0.f, 0.f};

#pragma unroll
    for (int n0 = 0; n0 < 8; ++n0) {
        const int prow = n0 * 16 + lr;
        const short8 b0 = *(const short8*)((const char*)Xl + swz(prow, lh * 16));
        const short8 b1 = *(const short8*)((const char*)Xl + swz(prow, 64 + lh * 16));
#pragma unroll
        for (int m0 = 0; m0 < 2; ++m0) {
            acc[m0][n0] = __builtin_amdgcn_mfma_f32_16x16x32_bf16(afr[m0][0], b0, acc[m0][n0], 0, 0, 0);
            acc[m0][n0] = __builtin_amdgcn_mfma_f32_16x16x32_bf16(afr[m0][1], b1, acc[m0][n0], 0, 0, 0);
        }
    }

    float scv[2][4], ofv[2][4];
#pragma unroll
    for (int m0 = 0; m0 < 2; ++m0)
#pragma unroll
        for (int r = 0; r < 4; ++r) {
            const int o = wv_ * 32 + m0 * 16 + lh * 4 + r;
            scv[m0][r] = sc[o];
            ofv[m0][r] = of[o];
        }

    const size_t ybase = (size_t)(n * COUT) * YSTR;
#pragma unroll
    for (int m0 = 0; m0 < 2; ++m0)
#pragma unroll
        for (int n0 = 0; n0 < 8; ++n0)
#pragma unroll
            for (int r = 0; r < 4; ++r) {
                const int o = wv_ * 32 + m0 * 16 + lh * 4 + r;
                const int pos = posbase + n0 * 16 + lr;
                const int t = pos / 25;
                const int v = pos - t * 25;
                const float val = acc[m0][n0][r] * scv[m0][r] + ofv[m0][r];
                y[ybase + (size_t)o * YSTR + t * YROW + v] = (unsigned short)f2b(val);
            }
}

// ---------------- Kernel B: temporal-window attention (single pass) ----------------
// 2048 blocks x 256 threads, 1 t per thread. Waves 0,1 -> even t; waves 2,3 ->
// odd t (row parity wave-uniform -> compile-time dword selects via template).
// Rows 56B: lane row-stride 2 -> dword-stride 28, gcd(28,32)=4 -> conflict-free.
// Online softmax WITHOUT max-subtract (|s|<~40 << 88): each row read ONCE:
// den += e = exp(dot/25); o_sm += e*row; o_a0 += att0_j*row; out = o_sm/den + o_a0.
#define UC(u,cc) ((cc)==0?(u).x:((cc)==1?(u).y:((cc)==2?(u).z:(u).w)))
#define DW(k) ((k)<4?UC(u0_,(k)):((k)<8?UC(u1_,(k)-4):((k)<12?UC(u2_,(k)-8):UC(u3_,(k)-12))))
#define LOADROW(rl, par, dst)                                               \
    {                                                                       \
        const int ub_ = (7 * (rl) - (par)) >> 1;                            \
        const uint4 u0_ = tl[ub_], u1_ = tl[ub_ + 1];                       \
        const uint4 u2_ = tl[ub_ + 2], u3_ = tl[ub_ + 3];                   \
        _Pragma("unroll")                                                   \
        for (int v_ = 0; v_ < 25; ++v_) {                                   \
            const int k_ = 2 * (par) + (v_ >> 1);                           \
            const unsigned dw_ = DW(k_);                                    \
            (dst)[v_] = (v_ & 1) ? hif(dw_) : lof(dw_);                     \
        }                                                                   \
    }

template<int PAR>
__device__ __forceinline__ void attn_core(const uint4* tl, const float* a0s,
                                          int t, float* outv)
{
    // q = center row (local rl = t+4, parity PAR since halo=4 is even)
    float q[25];
    LOADROW(t + 4, PAR, q);

    float osm[25], oa0[25];
    float den;
    {   // j = 4: self term, row == q (no LDS re-read)
        float d0 = 0.f, d1 = 0.f;
#pragma unroll
        for (int v = 0; v < 12; ++v)  d0 = fmaf(q[v], q[v], d0);
#pragma unroll
        for (int v = 12; v < 25; ++v) d1 = fmaf(q[v], q[v], d1);
        const float e = __expf((d0 + d1) * (1.f / 25.f));
        den = e;
        const float a = a0s[4];
#pragma unroll
        for (int v = 0; v < 25; ++v) { osm[v] = e * q[v]; oa0[v] = a * q[v]; }
    }

#pragma unroll
    for (int j = 0; j < KW; ++j) {
        if (j == 4) continue;
        float row[25];
        LOADROW(t + j, PAR ^ (j & 1), row);
        float d0 = 0.f, d1 = 0.f;
#pragma unroll
        for (int v = 0; v < 12; ++v)  d0 = fmaf(row[v], q[v], d0);
#pragma unroll
        for (int v = 12; v < 25; ++v) d1 = fmaf(row[v], q[v], d1);
        const float e = __expf((d0 + d1) * (1.f / 25.f));
        den += e;
        const float a = a0s[j];
#pragma unroll
        for (int v = 0; v < 25; ++v) {
            osm[v] = fmaf(e, row[v], osm[v]);
            oa0[v] = fmaf(a, row[v], oa0[v]);
        }
    }

    const float inv = 1.f / den;
#pragma unroll
    for (int v = 0; v < 25; ++v) outv[v] = fmaf(osm[v], inv, oa0[v]);
}

__global__ __launch_bounds__(256) void attn_kernel(
    const unsigned short* __restrict__ y, const float* __restrict__ att0,
    float* __restrict__ out)
{
    __shared__ __align__(16) float sm[TV];   // 25.6 KB: bf16 tile, then fp32 overlay
    __shared__ float a0s[KW];

    uint4* tl = (uint4*)sm;           // tile: 924 uint4 = 14784 B

    const int nc  = blockIdx.x;       // n*COUT + c
    const int c   = nc & (COUT - 1);
    const int tid = threadIdx.x;

    if (tid < KW) a0s[tid] = att0[c * KW + tid];

    // zero halo: front uint4 [0,14) (rows -4..-1), back [910,924) (rows 256..259)
    if (tid < 28) {
        const int i = (tid < 14) ? tid : (896 + tid);
        tl[i] = make_uint4(0, 0, 0, 0);
    }
    // stage: pure linear copy, 896 uint4, fully coalesced
    const uint4* yg = (const uint4*)(y + (size_t)nc * YSTR);
#pragma unroll
    for (int i = 0; i < 4; ++i) {
        const int ci = tid + i * 256;
        if (ci < 896) tl[14 + ci] = yg[ci];
    }
    __syncthreads();

    // wave-uniform parity mapping: waves 0,1 -> even t; waves 2,3 -> odd t
    const int w   = tid >> 6;
    const int par = (w >> 1) & 1;
    const int t   = ((w & 1) << 7) + ((tid & 63) << 1) + par;

    float outv[25];
    if (par == 0) attn_core<0>(tl, a0s, t, outv);
    else          attn_core<1>(tl, a0s, t, outv);

    // ---- overlay pack (scalar b32: odd-t bases are only 4B aligned) ----
    __syncthreads();
    {
        float* dst = &sm[t * 25];
#pragma unroll
        for (int v = 0; v < 25; ++v) dst[v] = outv[v];
    }
    __syncthreads();

    // ---- block-contiguous float4 stores: full 64B lines per instruction ----
    {
        float4* og = (float4*)(out + (size_t)nc * TV);
        const float4* sm4 = (const float4*)sm;
#pragma unroll
        for (int i = 0; i < 7; ++i) {
            const int ci = tid + i * 256;
            if (ci < TV / 4) og[ci] = sm4[ci];
        }
    }
}

extern "C" void kernel_launch(void* const* d_in, const int* in_sizes, int n_in,
                              void* d_out, int out_size, void* d_ws, size_t ws_size,
                              hipStream_t stream)
{
    const float* x     = (const float*)d_in[0];
    const float* w     = (const float*)d_in[1];
    const float* cb    = (const float*)d_in[2];
    const float* gamma = (const float*)d_in[3];
    const float* beta  = (const float*)d_in[4];
    const float* rm    = (const float*)d_in[5];
    const float* rv    = (const float*)d_in[6];
    const float* att0  = (const float*)d_in[7];
    float* out = (float*)d_out;
    unsigned short* y = (unsigned short*)d_ws;   // 2048*7168*2 = 29.4 MB padded bf16

    dim3 gA(TV / 128, 16);   // 50 x 16
    conv_mfma<<<gA, 256, 0, stream>>>(x, w, cb, gamma, beta, rm, rv, y);

    dim3 gB(16 * COUT);
    attn_kernel<<<gB, 256, 0, stream>>>(y, att0, out);
}

// Round 10
// 44.638 us; speedup vs baseline: 1.5054x; 1.5054x over previous
//
#include <hip/hip_runtime.h>
#include <hip/hip_bf16.h>

#define CIN   64
#define COUT  128
#define TT    256
#define VV    25
#define TV    (TT * VV)   // 6400
#define KW    9
#define PAD   4
#define YROW  28          // padded bf16 y row: 56B
#define YSTR  (TT * YROW) // 7168 shorts per (n,c) plane

typedef __attribute__((ext_vector_type(8))) short short8;   // 8 bf16 (4 VGPRs)
typedef __attribute__((ext_vector_type(4))) float f32x4;

__device__ __forceinline__ unsigned f2b(float f) {          // fp32 -> bf16 bits (RNE)
    unsigned u = __builtin_bit_cast(unsigned, f);
    return (u + 0x7FFFu + ((u >> 16) & 1u)) >> 16;
}
__device__ __forceinline__ float lof(unsigned u) {          // low bf16 -> f32
    return __builtin_bit_cast(float, u << 16);
}
__device__ __forceinline__ float hif(unsigned u) {          // high bf16 -> f32
    return __builtin_bit_cast(float, u & 0xffff0000u);
}
// conv LDS tile swizzle: [row][128B], XOR slot with (row&7)
__device__ __forceinline__ int swz(int row, int cbyte) {
    return row * 128 + ((cbyte & ~15) ^ ((row & 7) << 4)) + (cbyte & 15);
}

// ---------------- Kernel A: 1x1 conv + BN via bf16 MFMA (unchanged) ----------------
__global__ __launch_bounds__(256) void conv_mfma(
    const float* __restrict__ x, const float* __restrict__ w,
    const float* __restrict__ cb, const float* __restrict__ gamma,
    const float* __restrict__ beta, const float* __restrict__ rm,
    const float* __restrict__ rv, unsigned short* __restrict__ y)
{
    __shared__ __align__(16) unsigned short Wl[COUT * 64];   // 16 KB, swizzled
    __shared__ __align__(16) unsigned short Xl[128 * 64];    // 16 KB, swizzled [pos][c]
    __shared__ float sc[COUT];
    __shared__ float of[COUT];

    const int pc  = blockIdx.x;       // 0..49
    const int n   = blockIdx.y;       // 0..15
    const int tid = threadIdx.x;
    const int posbase = pc * 128;

    if (tid < COUT) {
        const float s = gamma[tid] * rsqrtf(rv[tid] + 1e-5f);
        sc[tid] = s;
        of[tid] = cb[tid] * s + beta[tid] - rm[tid] * s;
    }
    for (int idx = tid; idx < 2048; idx += 256) {
        const int c4 = idx & 15, o = idx >> 4;
        const f32x4 wv = *(const f32x4*)(w + o * 64 + c4 * 4);
        uint2 pk;
        pk.x = f2b(wv.x) | (f2b(wv.y) << 16);
        pk.y = f2b(wv.z) | (f2b(wv.w) << 16);
        *(uint2*)((char*)Wl + swz(o, c4 * 8)) = pk;
    }
    for (int idx = tid; idx < 2048; idx += 256) {
        const int pos = idx & 127, c4 = idx >> 7;
        const float* xp = x + (size_t)n * CIN * TV + (size_t)(c4 * 4) * TV + posbase + pos;
        const float a0 = xp[0], a1 = xp[TV], a2 = xp[2 * TV], a3 = xp[3 * TV];
        uint2 pk;
        pk.x = f2b(a0) | (f2b(a1) << 16);
        pk.y = f2b(a2) | (f2b(a3) << 16);
        *(uint2*)((char*)Xl + swz(pos, c4 * 8)) = pk;
    }
    __syncthreads();

    const int wv_ = tid >> 6, lane = tid & 63;
    const int lr = lane & 15, lh = lane >> 4;   // lh in 0..3

    short8 afr[2][2];
#pragma unroll
    for (int m0 = 0; m0 < 2; ++m0)
#pragma unroll
        for (int kh = 0; kh < 2; ++kh)
            afr[m0][kh] = *(const short8*)((const char*)Wl +
                              swz(wv_ * 32 + m0 * 16 + lr, kh * 64 + lh * 16));

    f32x4 acc[2][8];
#pragma unroll
    for (int m0 = 0; m0 < 2; ++m0)
#pragma unroll
        for (int n0 = 0; n0 < 8; ++n0) acc[m0][n0] = (f32x4){0.f, 0.f, 0.f, 0.f};

#pragma unroll
    for (int n0 = 0; n0 < 8; ++n0) {
        const int prow = n0 * 16 + lr;
        const short8 b0 = *(const short8*)((const char*)Xl + swz(prow, lh * 16));
        const short8 b1 = *(const short8*)((const char*)Xl + swz(prow, 64 + lh * 16));
#pragma unroll
        for (int m0 = 0; m0 < 2; ++m0) {
            acc[m0][n0] = __builtin_amdgcn_mfma_f32_16x16x32_bf16(afr[m0][0], b0, acc[m0][n0], 0, 0, 0);
            acc[m0][n0] = __builtin_amdgcn_mfma_f32_16x16x32_bf16(afr[m0][1], b1, acc[m0][n0], 0, 0, 0);
        }
    }

    float scv[2][4], ofv[2][4];
#pragma unroll
    for (int m0 = 0; m0 < 2; ++m0)
#pragma unroll
        for (int r = 0; r < 4; ++r) {
            const int o = wv_ * 32 + m0 * 16 + lh * 4 + r;
            scv[m0][r] = sc[o];
            ofv[m0][r] = of[o];
        }

    const size_t ybase = (size_t)(n * COUT) * YSTR;
#pragma unroll
    for (int m0 = 0; m0 < 2; ++m0)
#pragma unroll
        for (int n0 = 0; n0 < 8; ++n0)
#pragma unroll
            for (int r = 0; r < 4; ++r) {
                const int o = wv_ * 32 + m0 * 16 + lh * 4 + r;
                const int pos = posbase + n0 * 16 + lr;
                const int t = pos / 25;
                const int v = pos - t * 25;
                const float val = acc[m0][n0][r] * scv[m0][r] + ofv[m0][r];
                y[ybase + (size_t)o * YSTR + t * YROW + v] = (unsigned short)f2b(val);
            }
}

// ---------------- Kernel B: temporal-window attention ----------------
// 2048 blocks x 256 threads, t = tid (lane->row stride 1!). Rows 56B = 14
// dwords: 16 consecutive lanes' b64 starts = 14*l mod 32 = all 16 distinct
// evens -> each 16-lane group tiles all 32 banks exactly: conflict-FREE
// (the stride-2 maps of R2..R9 were 4-16 way conflicted, 6.16M cycles).
// Rows always uint2-aligned (14 even) -> no parity cases.
// Single pass, no-max online softmax (|s| <= ~40 << 88): row read once.
#define LOADROW(lr, dst)                                                    \
    {                                                                       \
        const int ub_ = 7 * (lr);                                           \
        const uint2 r0_ = tl2[ub_],     r1_ = tl2[ub_ + 1];                 \
        const uint2 r2_ = tl2[ub_ + 2], r3_ = tl2[ub_ + 3];                 \
        const uint2 r4_ = tl2[ub_ + 4], r5_ = tl2[ub_ + 5];                 \
        const unsigned l_ = tlu[14 * (lr) + 12];                            \
        (dst)[0]  = lof(r0_.x); (dst)[1]  = hif(r0_.x);                     \
        (dst)[2]  = lof(r0_.y); (dst)[3]  = hif(r0_.y);                     \
        (dst)[4]  = lof(r1_.x); (dst)[5]  = hif(r1_.x);                     \
        (dst)[6]  = lof(r1_.y); (dst)[7]  = hif(r1_.y);                     \
        (dst)[8]  = lof(r2_.x); (dst)[9]  = hif(r2_.x);                     \
        (dst)[10] = lof(r2_.y); (dst)[11] = hif(r2_.y);                     \
        (dst)[12] = lof(r3_.x); (dst)[13] = hif(r3_.x);                     \
        (dst)[14] = lof(r3_.y); (dst)[15] = hif(r3_.y);                     \
        (dst)[16] = lof(r4_.x); (dst)[17] = hif(r4_.x);                     \
        (dst)[18] = lof(r4_.y); (dst)[19] = hif(r4_.y);                     \
        (dst)[20] = lof(r5_.x); (dst)[21] = hif(r5_.x);                     \
        (dst)[22] = lof(r5_.y); (dst)[23] = hif(r5_.y);                     \
        (dst)[24] = lof(l_);                                                \
    }

__global__ __launch_bounds__(256) void attn_kernel(
    const unsigned short* __restrict__ y, const float* __restrict__ att0,
    float* __restrict__ out)
{
    __shared__ __align__(16) float sm[TV];   // 25.6 KB: bf16 tile (14.8KB), then fp32 overlay
    __shared__ float a0s[KW];

    uint4* tl4 = (uint4*)sm;                  // tile: 924 uint4 = 14784 B
    const uint2* tl2 = (const uint2*)sm;
    const unsigned* tlu = (const unsigned*)sm;

    const int nc  = blockIdx.x;       // n*COUT + c
    const int c   = nc & (COUT - 1);
    const int tid = threadIdx.x;

    if (tid < KW) a0s[tid] = att0[c * KW + tid];

    // zero halo: front uint4 [0,14) (rows -4..-1), back [910,924) (rows 256..259)
    if (tid < 28) {
        const int i = (tid < 14) ? tid : (896 + tid);
        tl4[i] = make_uint4(0, 0, 0, 0);
    }
    // stage: linear copy, 896 uint4, fully coalesced; writes stride-4-dword -> conflict-free
    const uint4* yg = (const uint4*)(y + (size_t)nc * YSTR);
#pragma unroll
    for (int i = 0; i < 4; ++i) {
        const int ci = tid + i * 256;
        if (ci < 896) tl4[14 + ci] = yg[ci];
    }
    __syncthreads();

    const int t = tid;                // local center row = t + 4

    float q[25];
    LOADROW(t + 4, q);

    float osm[25], oa0[25];
    float den;
    {   // j = 4: self term (row == q, no LDS read)
        float d0 = 0.f, d1 = 0.f;
#pragma unroll
        for (int v = 0; v < 12; ++v)  d0 = fmaf(q[v], q[v], d0);
#pragma unroll
        for (int v = 12; v < 25; ++v) d1 = fmaf(q[v], q[v], d1);
        const float e = __expf((d0 + d1) * (1.f / 25.f));
        den = e;
        const float a = a0s[4];
#pragma unroll
        for (int v = 0; v < 25; ++v) { osm[v] = e * q[v]; oa0[v] = a * q[v]; }
    }

#pragma unroll
    for (int j = 0; j < KW; ++j) {
        if (j == 4) continue;
        float row[25];
        LOADROW(t + j, row);
        float d0 = 0.f, d1 = 0.f;
#pragma unroll
        for (int v = 0; v < 12; ++v)  d0 = fmaf(row[v], q[v], d0);
#pragma unroll
        for (int v = 12; v < 25; ++v) d1 = fmaf(row[v], q[v], d1);
        const float e = __expf((d0 + d1) * (1.f / 25.f));
        den += e;
        const float a = a0s[j];
#pragma unroll
        for (int v = 0; v < 25; ++v) {
            osm[v] = fmaf(e, row[v], osm[v]);
            oa0[v] = fmaf(a, row[v], oa0[v]);
        }
    }

    const float inv = 1.f / den;

    // ---- overlay pack: lane stride 25 dwords (odd) -> conflict-light ----
    __syncthreads();
    {
        float* dst = &sm[t * 25];
#pragma unroll
        for (int v = 0; v < 25; ++v) dst[v] = fmaf(osm[v], inv, oa0[v]);
    }
    __syncthreads();

    // ---- block-contiguous float4 stores: full 64B lines per instruction ----
    {
        float4* og = (float4*)(out + (size_t)nc * TV);
        const float4* sm4 = (const float4*)sm;
#pragma unroll
        for (int i = 0; i < 7; ++i) {
            const int ci = tid + i * 256;
            if (ci < TV / 4) og[ci] = sm4[ci];
        }
    }
}

extern "C" void kernel_launch(void* const* d_in, const int* in_sizes, int n_in,
                              void* d_out, int out_size, void* d_ws, size_t ws_size,
                              hipStream_t stream)
{
    const float* x     = (const float*)d_in[0];
    const float* w     = (const float*)d_in[1];
    const float* cb    = (const float*)d_in[2];
    const float* gamma = (const float*)d_in[3];
    const float* beta  = (const float*)d_in[4];
    const float* rm    = (const float*)d_in[5];
    const float* rv    = (const float*)d_in[6];
    const float* att0  = (const float*)d_in[7];
    float* out = (float*)d_out;
    unsigned short* y = (unsigned short*)d_ws;   // 2048*7168*2 = 29.4 MB padded bf16

    dim3 gA(TV / 128, 16);   // 50 x 16
    conv_mfma<<<gA, 256, 0, stream>>>(x, w, cb, gamma, beta, rm, rv, y);

    dim3 gB(16 * COUT);
    attn_kernel<<<gB, 256, 0, stream>>>(y, att0, out);
}